// Round 12
// baseline (166.526 us; speedup 1.0000x reference)
//
#include <hip/hip_runtime.h>
#include <stdint.h>

typedef unsigned int u32;
typedef int v4i  __attribute__((ext_vector_type(4)));
typedef int v16i __attribute__((ext_vector_type(16)));

#define K_MSG   1024
#define N_CODE  2048
#define NB      32768

// ------------- pack G -> fragment-major i8 B (proven round 10/11) -----------
// BF tile = one MFMA B-fragment (32 cols x 32 k) = 1024 B in LANE order:
// a wave's frag load is base + lane*16 -> one fully-coalesced dwordx4.
__global__ void pack_gBF(const int* __restrict__ G, u32* __restrict__ bf) {
    int idx = blockIdx.x * blockDim.x + threadIdx.x;   // 524288
    const int j  = idx & (N_CODE - 1);                 // coalesced G reads
    const int kq = idx >> 11;                          // dword of k: 0..255
    u32 p = 0;
#pragma unroll
    for (int i = 0; i < 4; ++i) {
        int v = G[(size_t)(kq * 4 + i) * N_CODE + j];
        p |= (u32)(v & 1) << (8 * i);
    }
    const int jb = j >> 5, jr = j & 31;
    const int kb = kq >> 3, hi = (kq >> 2) & 1, b4 = kq & 3;
    bf[(size_t)(jb * 32 + kb) * 256 + hi * 128 + jr * 4 + b4] = p;
}

// ---------------- fused pack+GEMM -------------------------------------------
// Block = 4 waves, owns a 64-row M-panel for ALL 2048 cols (4 passes of 512).
// Stage: block packs its own b-panel (64x1024 int32 -> i8) into 64KB LDS
// (XOR-swizzled), ONE barrier. Then 4 passes: round-10's barrier-free k-loop
// (wave tile 64x128, 4-deep named pipeline, fragment-major B from L2) + per-
// pass store burst -> stores overlap the next pass's compute.

#define MFMA_I8(va, vb, vc) __builtin_amdgcn_mfma_i32_32x32x32_i8(va, vb, vc, 0, 0, 0)

#define MFMA_SET(sfx) do {                              \
    acc[0][0] = MFMA_I8(a0##sfx, b0##sfx, acc[0][0]);   \
    acc[0][1] = MFMA_I8(a0##sfx, b1##sfx, acc[0][1]);   \
    acc[0][2] = MFMA_I8(a0##sfx, b2##sfx, acc[0][2]);   \
    acc[0][3] = MFMA_I8(a0##sfx, b3##sfx, acc[0][3]);   \
    acc[1][0] = MFMA_I8(a1##sfx, b0##sfx, acc[1][0]);   \
    acc[1][1] = MFMA_I8(a1##sfx, b1##sfx, acc[1][1]);   \
    acc[1][2] = MFMA_I8(a1##sfx, b2##sfx, acc[1][2]);   \
    acc[1][3] = MFMA_I8(a1##sfx, b3##sfx, acc[1][3]);   \
} while (0)

#define LOAD_SET(sfx, s_) do {                                      \
    int ao_ = lr * 1024 + ((((s_) * 32) + hi * 16) ^ axor);         \
    a0##sfx = *(const v4i*)(As + ao_);                              \
    a1##sfx = *(const v4i*)(As + ao_ + 32768);                      \
    b0##sfx = *(const v4i*)(bp0 + (size_t)(s_) * 1024);             \
    b1##sfx = *(const v4i*)(bp1 + (size_t)(s_) * 1024);             \
    b2##sfx = *(const v4i*)(bp2 + (size_t)(s_) * 1024);             \
    b3##sfx = *(const v4i*)(bp3 + (size_t)(s_) * 1024);             \
} while (0)

__global__ __launch_bounds__(256, 2) void gemm_fused(const int* __restrict__ b,
                                                     const char* __restrict__ bf,
                                                     int* __restrict__ out) {
    __shared__ __align__(16) char As[64 * 1024];    // 64 KB: 64 rows x 1024 B

    const int t  = threadIdx.x;
    const int m0 = blockIdx.x * 64;
    const int w = t >> 6, lane = t & 63, lr = lane & 31, hi = lane >> 5;
    const int axor = (lr & 7) << 4;

    // ---- stage: pack own b-panel to i8 in LDS (row i, bytes t*4..t*4+3) ----
    {
        const int* src = b + (size_t)m0 * K_MSG;
#pragma unroll 8
        for (int i = 0; i < 64; ++i) {
            int4 v = *(const int4*)(src + (size_t)i * K_MSG + t * 4); // coalesced
            u32 p = (u32)(v.x & 1) | ((u32)(v.y & 1) << 8) |
                    ((u32)(v.z & 1) << 16) | ((u32)(v.w & 1) << 24);
            *(u32*)(As + i * 1024 + ((t * 4) ^ ((i & 7) << 4))) = p;
        }
    }
    __syncthreads();    // the only barrier

#pragma unroll 1
    for (int pass = 0; pass < 4; ++pass) {
        // fragment-major B bases: colblk = pass*16 + w*4 + ni, frag stride 32KB
        const char* bp0 = bf + ((size_t)pass * 16 + w * 4) * 32768 + lane * 16;
        const char* bp1 = bp0 + 32768;
        const char* bp2 = bp0 + 65536;
        const char* bp3 = bp0 + 98304;

        v16i acc[2][4] = {};
        v4i a0A, a1A, b0A, b1A, b2A, b3A;
        v4i a0B, a1B, b0B, b1B, b2B, b3B;
        v4i a0C, a1C, b0C, b1C, b2C, b3C;
        v4i a0D, a1D, b0D, b1D, b2D, b3D;

        LOAD_SET(A, 0);
        LOAD_SET(B, 1);
#pragma unroll 1
        for (int s = 0; s < 32; s += 4) {
            LOAD_SET(C, s + 2);
            LOAD_SET(D, s + 3);
            MFMA_SET(A);
            MFMA_SET(B);
            if (s + 4 < 32) {
                LOAD_SET(A, s + 4);
                LOAD_SET(B, s + 5);
            }
            MFMA_SET(C);
            MFMA_SET(D);
        }

        // per-pass store burst (overlaps next pass's compute via vmcnt slack)
        // C/D map (verified): col=lane&31, row=(r&3)+8*(r>>2)+4*hi
#pragma unroll
        for (int mi = 0; mi < 2; ++mi) {
#pragma unroll
            for (int ni = 0; ni < 4; ++ni) {
                const int cbase = pass * 512 + w * 128 + ni * 32 + lr;
                const int rbase = m0 + mi * 32 + 4 * hi;
#pragma unroll
                for (int r = 0; r < 16; ++r) {
                    const int row = rbase + (r & 3) + 8 * (r >> 2);
                    out[(size_t)row * N_CODE + cbase] = acc[mi][ni][r] & 1;
                }
            }
        }
    }
}

// ---------------- fallback (only if ws too small) ---------------------------
__global__ void encode_naive(const int* __restrict__ b, const int* __restrict__ G,
                             int* __restrict__ out) {
    size_t idx = (size_t)blockIdx.x * blockDim.x + threadIdx.x;
    size_t total = (size_t)NB * N_CODE;
    if (idx >= total) return;
    int i = (int)(idx / N_CODE);
    int j = (int)(idx % N_CODE);
    int acc = 0;
    for (int k = 0; k < K_MSG; ++k)
        acc ^= b[(size_t)i * K_MSG + k] & G[(size_t)k * N_CODE + j];
    out[idx] = acc & 1;
}

extern "C" void kernel_launch(void* const* d_in, const int* in_sizes, int n_in,
                              void* d_out, int out_size, void* d_ws, size_t ws_size,
                              hipStream_t stream) {
    const int* b = (const int*)d_in[0];
    const int* G = (const int*)d_in[1];
    int* out = (int*)d_out;

    const size_t bf_bytes = (size_t)N_CODE * K_MSG;      // 2 MiB

    if (ws_size < bf_bytes) {
        size_t total = (size_t)NB * N_CODE;
        encode_naive<<<(unsigned)((total + 255) / 256), 256, 0, stream>>>(b, G, out);
        return;
    }

    char* bf = (char*)d_ws;

    pack_gBF<<<2048, 256, 0, stream>>>(G, (u32*)bf);
    gemm_fused<<<NB / 64, 256, 0, stream>>>(b, bf, out);   // 512 blocks
}